// Round 1
// baseline (436.232 us; speedup 1.0000x reference)
//
#include <hip/hip_runtime.h>

// Problem constants (from reference)
#define N_NODES 200000
#define DIM 128                 // node / nig embedding dim
#define HID 256                 // hidden dim
#define BATCH 8192
#define SIDE_FLOATS (N_NODES * DIM)   // 25,600,000 floats per side

// ---------------------------------------------------------------------------
// Kernel 1: fold the affine chain into one [2*DIM, DIM] matrix + [DIM] bias
// per side.  node = x @ Mf[0:128] + n @ Mf[128:256] + bias
// Mf[k][j]  (k<128):  sum_h Wr[k][h] * Wo[h][j]
// Mf[k][j]  (k>=128): sum_h Wn[k-128][h] * Wo[256+h][j]
// bias[j] = bo[j] + sum_h br[h]*Wo[h][j] + sum_h bn[h]*Wo[256+h][j]
// ---------------------------------------------------------------------------
__global__ __launch_bounds__(128) void precompute_kernel(
    const float* __restrict__ Wr0, const float* __restrict__ Wn0, const float* __restrict__ Wo0,
    const float* __restrict__ br0, const float* __restrict__ bn0, const float* __restrict__ bo0,
    const float* __restrict__ Wr1, const float* __restrict__ Wn1, const float* __restrict__ Wo1,
    const float* __restrict__ br1, const float* __restrict__ bn1, const float* __restrict__ bo1,
    float* __restrict__ Mf, float* __restrict__ bias)
{
    const int s = blockIdx.y;
    const float* Wr = s ? Wr1 : Wr0;
    const float* Wn = s ? Wn1 : Wn0;
    const float* Wo = s ? Wo1 : Wo0;
    const float* br = s ? br1 : br0;
    const float* bn = s ? bn1 : bn0;
    const float* bo = s ? bo1 : bo0;
    const int j = threadIdx.x;     // output column 0..127
    const int k = blockIdx.x;      // fused-matrix row 0..255, or 256 for bias

    if (k < 2 * DIM) {
        __shared__ float w[HID];
        const float* wrow = (k < DIM) ? (Wr + k * HID) : (Wn + (k - DIM) * HID);
        const float* wo   = (k < DIM) ? Wo : (Wo + HID * DIM);
        w[j]       = wrow[j];
        w[j + DIM] = wrow[j + DIM];
        __syncthreads();
        float acc = 0.f;
        #pragma unroll 8
        for (int h = 0; h < HID; ++h) acc += w[h] * wo[h * DIM + j];
        Mf[((s << 8) + k) * DIM + j] = acc;
    } else {
        float acc = bo[j];
        for (int h = 0; h < HID; ++h) acc += br[h] * Wo[h * DIM + j];
        for (int h = 0; h < HID; ++h) acc += bn[h] * Wo[(HID + h) * DIM + j];
        bias[s * DIM + j] = acc;
    }
}

// ---------------------------------------------------------------------------
// Kernel 2: bulk copy both previous embeddings into d_out (float4, grid-stride)
// ---------------------------------------------------------------------------
__global__ __launch_bounds__(256) void copy_kernel(
    const float4* __restrict__ a, const float4* __restrict__ b,
    float4* __restrict__ out, long n4side)
{
    long i = (long)blockIdx.x * blockDim.x + threadIdx.x;
    const long stride = (long)gridDim.x * blockDim.x;
    const long total = 2 * n4side;
    for (; i < total; i += stride) {
        out[i] = (i < n4side) ? a[i] : b[i - n4side];
    }
}

// ---------------------------------------------------------------------------
// Kernel 3: node_emb = concat(prev[ids], nig) @ Mf + bias, scattered into out.
// Block = 256 threads, handles RB=32 batch rows.  Thread (rg,jg) computes a
// 4x4 micro-tile: rows rg*4..+3, cols jg*4..+3.
// ---------------------------------------------------------------------------
#define RB 32
#define CAT_STRIDE 260   // pad: keeps float4 alignment (260*4 % 16 == 0) and
                         // rg-groups 16 banks apart -> conflict-free

__global__ __launch_bounds__(256) void update_kernel(
    const int* __restrict__ ids0, const float* __restrict__ prev0, const float* __restrict__ nig0,
    const int* __restrict__ ids1, const float* __restrict__ prev1, const float* __restrict__ nig1,
    const float* __restrict__ Mf, const float* __restrict__ bias,
    float* __restrict__ out)
{
    const int s = blockIdx.y;
    const int*   ids  = s ? ids1  : ids0;
    const float* prev = s ? prev1 : prev0;
    const float* nig  = s ? nig1  : nig0;
    const float* M    = Mf + s * (2 * DIM) * DIM;
    const float* bs   = bias + s * DIM;
    float* outs = out + (size_t)s * SIDE_FLOATS;

    __shared__ int   sid[RB];
    __shared__ float cat[RB][CAT_STRIDE];

    const int tid = threadIdx.x;
    const int b0  = blockIdx.x * RB;

    if (tid < RB) sid[tid] = ids[b0 + tid];
    __syncthreads();

    // Stage concat(prev[ids[b]], nig[b]) for the 32 rows: 32 x 64 float4 loads
    for (int idx = tid; idx < RB * 64; idx += 256) {
        const int r = idx >> 6;        // row 0..31
        const int q = idx & 63;        // q-th float4 within the 256-float row
        float4 v;
        if (q < 32) v = ((const float4*)(prev + (size_t)sid[r] * DIM))[q];
        else        v = ((const float4*)(nig  + (size_t)(b0 + r) * DIM))[q - 32];
        *(float4*)&cat[r][q * 4] = v;
    }
    __syncthreads();

    const int jg = tid & 31;   // column group (4 cols)
    const int rg = tid >> 5;   // row group (4 rows), 0..7

    float acc[4][4];
    #pragma unroll
    for (int r = 0; r < 4; ++r)
        #pragma unroll
        for (int c = 0; c < 4; ++c) acc[r][c] = 0.f;

    const float4* M4 = (const float4*)M;
    #pragma unroll 4
    for (int k = 0; k < 2 * DIM; ++k) {
        const float4 m = M4[(k << 5) + jg];
        #pragma unroll
        for (int r = 0; r < 4; ++r) {
            const float a = cat[rg * 4 + r][k];
            acc[r][0] += a * m.x;
            acc[r][1] += a * m.y;
            acc[r][2] += a * m.z;
            acc[r][3] += a * m.w;
        }
    }

    const float4 bj = ((const float4*)bs)[jg];
    #pragma unroll
    for (int r = 0; r < 4; ++r) {
        const int row = sid[rg * 4 + r];
        float4 v;
        v.x = acc[r][0] + bj.x;
        v.y = acc[r][1] + bj.y;
        v.z = acc[r][2] + bj.z;
        v.w = acc[r][3] + bj.w;
        ((float4*)(outs + (size_t)row * DIM))[jg] = v;
    }
}

// ---------------------------------------------------------------------------
extern "C" void kernel_launch(void* const* d_in, const int* in_sizes, int n_in,
                              void* d_out, int out_size, void* d_ws, size_t ws_size,
                              hipStream_t stream) {
    const int*   src_ids   = (const int*)d_in[0];
    const int*   dst_ids   = (const int*)d_in[1];
    const float* src_prev  = (const float*)d_in[2];
    const float* dst_prev  = (const float*)d_in[3];
    const float* src_nig   = (const float*)d_in[4];
    const float* dst_nig   = (const float*)d_in[5];
    const float* W_src_nig     = (const float*)d_in[6];
    const float* b_src_nig     = (const float*)d_in[7];
    const float* W_src_resize  = (const float*)d_in[8];
    const float* b_src_resize  = (const float*)d_in[9];
    const float* W_src_out     = (const float*)d_in[10];
    const float* b_src_out     = (const float*)d_in[11];
    const float* W_dst_nig     = (const float*)d_in[12];
    const float* b_dst_nig     = (const float*)d_in[13];
    const float* W_dst_resize  = (const float*)d_in[14];
    const float* b_dst_resize  = (const float*)d_in[15];
    const float* W_dst_out     = (const float*)d_in[16];
    const float* b_dst_out     = (const float*)d_in[17];

    float* out  = (float*)d_out;
    float* Mf   = (float*)d_ws;              // 2 * 256 * 128 floats = 256 KB
    float* bias = Mf + 2 * (2 * DIM) * DIM;  // 2 * 128 floats

    // 1) fold weights
    precompute_kernel<<<dim3(2 * DIM + 1, 2), 128, 0, stream>>>(
        W_src_resize, W_src_nig, W_src_out, b_src_resize, b_src_nig, b_src_out,
        W_dst_resize, W_dst_nig, W_dst_out, b_dst_resize, b_dst_nig, b_dst_out,
        Mf, bias);

    // 2) bulk copy prev embeddings into out
    const long n4side = SIDE_FLOATS / 4;     // 6,400,000 float4 per side
    copy_kernel<<<4096, 256, 0, stream>>>(
        (const float4*)src_prev, (const float4*)dst_prev, (float4*)out, n4side);

    // 3) compute node embeddings and scatter
    update_kernel<<<dim3(BATCH / RB, 2), 256, 0, stream>>>(
        src_ids, src_prev, src_nig,
        dst_ids, dst_prev, dst_nig,
        Mf, bias, out);
}

// Round 3
// 404.804 us; speedup vs baseline: 1.0776x; 1.0776x over previous
//
#include <hip/hip_runtime.h>

// Problem constants (from reference)
#define N_NODES 200000
#define DIM 128                 // node / nig embedding dim
#define HID 256                 // hidden dim
#define BATCH 8192
#define SIDE_FLOATS (N_NODES * DIM)   // 25,600,000 floats per side
#define MAGIC 0x5EED1234u       // != 0xAAAAAAAA ws-poison

typedef float vf4 __attribute__((ext_vector_type(4)));  // native vector: OK for nontemporal builtins

// ---------------------------------------------------------------------------
// Kernel 1: fold the affine chain into one [2*DIM, DIM] matrix + [DIM] bias
// per side, and build the "row updated" flag arrays from ids.
//   node = x @ Mf[0:128] + n @ Mf[128:256] + bias
// Grid: x in [0, 257+64), y = side. x<256: Mf row; x==256: bias; x>=257: flags.
// ---------------------------------------------------------------------------
__global__ __launch_bounds__(128) void setup_kernel(
    const float* __restrict__ Wr0, const float* __restrict__ Wn0, const float* __restrict__ Wo0,
    const float* __restrict__ br0, const float* __restrict__ bn0, const float* __restrict__ bo0,
    const float* __restrict__ Wr1, const float* __restrict__ Wn1, const float* __restrict__ Wo1,
    const float* __restrict__ br1, const float* __restrict__ bn1, const float* __restrict__ bo1,
    const int* __restrict__ ids0, const int* __restrict__ ids1,
    float* __restrict__ Mf, float* __restrict__ bias,
    unsigned* __restrict__ flags0, unsigned* __restrict__ flags1)
{
    const int s = blockIdx.y;
    const int j = threadIdx.x;     // 0..127
    const int k = blockIdx.x;

    if (k < 2 * DIM) {
        const float* Wr = s ? Wr1 : Wr0;
        const float* Wn = s ? Wn1 : Wn0;
        const float* Wo = s ? Wo1 : Wo0;
        __shared__ float w[HID];
        const float* wrow = (k < DIM) ? (Wr + k * HID) : (Wn + (k - DIM) * HID);
        const float* wo   = (k < DIM) ? Wo : (Wo + HID * DIM);
        w[j]       = wrow[j];
        w[j + DIM] = wrow[j + DIM];
        __syncthreads();
        float acc = 0.f;
        #pragma unroll 8
        for (int h = 0; h < HID; ++h) acc += w[h] * wo[h * DIM + j];
        Mf[((s << 8) + k) * DIM + j] = acc;
    } else if (k == 2 * DIM) {
        const float* Wo = s ? Wo1 : Wo0;
        const float* br = s ? br1 : br0;
        const float* bn = s ? bn1 : bn0;
        const float* bo = s ? bo1 : bo0;
        float acc = bo[j];
        for (int h = 0; h < HID; ++h) acc += br[h] * Wo[h * DIM + j];
        for (int h = 0; h < HID; ++h) acc += bn[h] * Wo[(HID + h) * DIM + j];
        bias[s * DIM + j] = acc;
    } else {
        // flag-build: 64 blocks x 128 threads = 8192 = BATCH
        const int i = (k - (2 * DIM + 1)) * 128 + j;
        const int* ids   = s ? ids1 : ids0;
        unsigned*  fl    = s ? flags1 : flags0;
        fl[ids[i]] = MAGIC;
    }
}

// ---------------------------------------------------------------------------
// Kernel 2 (fused): blocks [0,512) compute+scatter node embeddings; blocks
// [512, 512+8192) stream-copy prev embeddings into out, skipping flagged rows.
// Writes are disjoint, so no intra-grid ordering is required.
// ---------------------------------------------------------------------------
#define RB 32
#define CAT_STRIDE 260   // float4-aligned (260*4%16==0); rg-groups 16 banks apart

#define COPY_BLOCKS_PER_SIDE 4096
#define ROW_GROUPS 25000          // 200000 rows / 8 rows-per-block-iteration

__global__ __launch_bounds__(256) void fused_kernel(
    const int* __restrict__ ids0, const float* __restrict__ prev0, const float* __restrict__ nig0,
    const int* __restrict__ ids1, const float* __restrict__ prev1, const float* __restrict__ nig1,
    const float* __restrict__ Mf, const float* __restrict__ bias,
    const unsigned* __restrict__ flags0, const unsigned* __restrict__ flags1,
    float* __restrict__ out)
{
    const int bx  = blockIdx.x;
    const int tid = threadIdx.x;

    if (bx < 512) {
        // ---- update path: 256 blocks per side, 32 batch rows per block ----
        const int s = bx >> 8;
        const int*   ids  = s ? ids1  : ids0;
        const float* prev = s ? prev1 : prev0;
        const float* nig  = s ? nig1  : nig0;
        const float* M    = Mf + s * (2 * DIM) * DIM;
        const float* bs   = bias + s * DIM;
        float* outs = out + (size_t)s * SIDE_FLOATS;

        __shared__ int   sid[RB];
        __shared__ float cat[RB][CAT_STRIDE];

        const int b0 = (bx & 255) * RB;

        if (tid < RB) sid[tid] = ids[b0 + tid];
        __syncthreads();

        for (int idx = tid; idx < RB * 64; idx += 256) {
            const int r = idx >> 6;
            const int q = idx & 63;
            float4 v;
            if (q < 32) v = ((const float4*)(prev + (size_t)sid[r] * DIM))[q];
            else        v = ((const float4*)(nig  + (size_t)(b0 + r) * DIM))[q - 32];
            *(float4*)&cat[r][q * 4] = v;
        }
        __syncthreads();

        const int jg = tid & 31;   // 4-col group
        const int rg = tid >> 5;   // 4-row group

        float acc[4][4];
        #pragma unroll
        for (int r = 0; r < 4; ++r)
            #pragma unroll
            for (int c = 0; c < 4; ++c) acc[r][c] = 0.f;

        const float4* M4 = (const float4*)M;
        #pragma unroll 4
        for (int k = 0; k < 2 * DIM; ++k) {
            const float4 m = M4[(k << 5) + jg];
            #pragma unroll
            for (int r = 0; r < 4; ++r) {
                const float a = cat[rg * 4 + r][k];
                acc[r][0] += a * m.x;
                acc[r][1] += a * m.y;
                acc[r][2] += a * m.z;
                acc[r][3] += a * m.w;
            }
        }

        const float4 bj = ((const float4*)bs)[jg];
        #pragma unroll
        for (int r = 0; r < 4; ++r) {
            const int row = sid[rg * 4 + r];
            float4 v;
            v.x = acc[r][0] + bj.x;
            v.y = acc[r][1] + bj.y;
            v.z = acc[r][2] + bj.z;
            v.w = acc[r][3] + bj.w;
            ((float4*)(outs + (size_t)row * DIM))[jg] = v;
        }
        return;
    }

    // ---- copy path: stream rows not in the update set ----
    const int cb   = bx - 512;
    const int side = cb >> 12;                 // 4096 blocks per side
    const int c    = cb & (COPY_BLOCKS_PER_SIDE - 1);
    const vf4*      p4 = (const vf4*)(side ? prev1 : prev0);
    const unsigned* fl = side ? flags1 : flags0;
    vf4* o4 = (vf4*)out + (size_t)side * (SIDE_FLOATS / 4);

    const int rloc = tid >> 5;    // 0..7 row within group
    const int q    = tid & 31;    // float4 lane within row

    #pragma unroll 2
    for (int g = c; g < ROW_GROUPS; g += COPY_BLOCKS_PER_SIDE) {
        const int row = (g << 3) + rloc;
        if (fl[row] != MAGIC) {
            const size_t idx = (size_t)row * 32 + q;
            vf4 v = __builtin_nontemporal_load(p4 + idx);
            __builtin_nontemporal_store(v, o4 + idx);
        }
    }
}

// ---------------------------------------------------------------------------
extern "C" void kernel_launch(void* const* d_in, const int* in_sizes, int n_in,
                              void* d_out, int out_size, void* d_ws, size_t ws_size,
                              hipStream_t stream) {
    const int*   src_ids   = (const int*)d_in[0];
    const int*   dst_ids   = (const int*)d_in[1];
    const float* src_prev  = (const float*)d_in[2];
    const float* dst_prev  = (const float*)d_in[3];
    const float* src_nig   = (const float*)d_in[4];
    const float* dst_nig   = (const float*)d_in[5];
    const float* W_src_nig     = (const float*)d_in[6];
    const float* b_src_nig     = (const float*)d_in[7];
    const float* W_src_resize  = (const float*)d_in[8];
    const float* b_src_resize  = (const float*)d_in[9];
    const float* W_src_out     = (const float*)d_in[10];
    const float* b_src_out     = (const float*)d_in[11];
    const float* W_dst_nig     = (const float*)d_in[12];
    const float* b_dst_nig     = (const float*)d_in[13];
    const float* W_dst_resize  = (const float*)d_in[14];
    const float* b_dst_resize  = (const float*)d_in[15];
    const float* W_dst_out     = (const float*)d_in[16];
    const float* b_dst_out     = (const float*)d_in[17];

    float* out  = (float*)d_out;
    float* Mf   = (float*)d_ws;                       // 2*256*128 floats
    float* bias = Mf + 2 * (2 * DIM) * DIM;           // 2*128 floats
    unsigned* flags0 = (unsigned*)(bias + 2 * DIM);   // N_NODES u32
    unsigned* flags1 = flags0 + N_NODES;              // N_NODES u32

    // 1) fold weights + build row flags (poison 0xAAAAAAAA == "not updated")
    setup_kernel<<<dim3(2 * DIM + 1 + BATCH / 128, 2), 128, 0, stream>>>(
        W_src_resize, W_src_nig, W_src_out, b_src_resize, b_src_nig, b_src_out,
        W_dst_resize, W_dst_nig, W_dst_out, b_dst_resize, b_dst_nig, b_dst_out,
        src_ids, dst_ids, Mf, bias, flags0, flags1);

    // 2) fused update + copy (disjoint writes; update hides under copy BW)
    fused_kernel<<<512 + 2 * COPY_BLOCKS_PER_SIDE, 256, 0, stream>>>(
        src_ids, src_prev, src_nig,
        dst_ids, dst_prev, dst_nig,
        Mf, bias, flags0, flags1, out);
}